// Round 5
// baseline (924.617 us; speedup 1.0000x reference)
//
#include <hip/hip_runtime.h>

#define DH 128   // D_IN == D_H == 128
#define TR 64    // rows per tile
#define NT 8     // tiles per block

typedef __attribute__((ext_vector_type(8))) short bf16x8;
typedef __attribute__((ext_vector_type(8))) unsigned short u16x8;
typedef __attribute__((ext_vector_type(4))) float f32x4;
typedef __attribute__((ext_vector_type(4))) int   i32x4;

__device__ inline unsigned rnd_bf16(float f){
  unsigned u = __builtin_bit_cast(unsigned, f);
  u += 0x7fffu + ((u >> 16) & 1u);   // RNE
  return u;
}
__device__ inline int pk2(float a, float b){
  unsigned ua = rnd_bf16(a), ub = rnd_bf16(b);
  return (int)((ua >> 16) | (ub & 0xffff0000u));
}
__device__ inline float fsigmoid(float v){
  float e = __builtin_amdgcn_exp2f(v * -1.442695040888963f);
  return __builtin_amdgcn_rcpf(1.0f + e);
}
__device__ inline float ftanhf(float v){
  float e = __builtin_amdgcn_exp2f(v * 2.885390081777927f); // e^{2v}
  return 1.0f - 2.0f * __builtin_amdgcn_rcpf(1.0f + e);
}

// Wf[hs 4][g 4][t 2][ks 8][lane 64] 16B fragments: lane (l15,lg) holds
// ncol = g*128 + hs*32 + t*16 + l15, k = ks*32 + lg*8 .. +8 (k<128: W_x, else W_h).
__global__ void prep_weights(const float* __restrict__ Wxi, const float* __restrict__ Whi, const float* __restrict__ bi,
                             const float* __restrict__ Wxf, const float* __restrict__ Whf, const float* __restrict__ bf_,
                             const float* __restrict__ Wxc, const float* __restrict__ Whc, const float* __restrict__ bc,
                             const float* __restrict__ Wxo, const float* __restrict__ Who, const float* __restrict__ bo,
                             u16x8* __restrict__ Wf, float* __restrict__ bcat){
  int gid  = blockIdx.x * 256 + threadIdx.x;   // 0..16383
  int lane = gid & 63;
  int ks   = (gid >> 6) & 7;
  int t    = (gid >> 9) & 1;
  int g    = (gid >> 10) & 3;
  int hsv  = (gid >> 12) & 3;
  int l15 = lane & 15, lg = lane >> 4;
  int hcol = hsv * 32 + t * 16 + l15;
  int kb   = ks * 32 + lg * 8;
  const float* Wx = (g == 0) ? Wxi : (g == 1) ? Wxf : (g == 2) ? Wxc : Wxo;
  const float* Wh = (g == 0) ? Whi : (g == 1) ? Whf : (g == 2) ? Whc : Who;
  u16x8 o;
  #pragma unroll
  for (int j = 0; j < 8; ++j){
    int k = kb + j;
    float v = (k < 128) ? Wx[k * DH + hcol] : Wh[(k - 128) * DH + hcol];
    o[j] = (unsigned short)(rnd_bf16(v) >> 16);
  }
  Wf[gid] = o;
  if (gid < 512){
    int gg = gid >> 7, hc = gid & 127;
    const float* bp = (gg == 0) ? bi : (gg == 1) ? bf_ : (gg == 2) ? bc : bo;
    bcat[gid] = bp[hc];
  }
}

// Persistent pipelined LSTM. 512 thr = 8 waves.
// Waves 0-3: rows [0,32); waves 4-7: rows [32,64). Wave (wid&3) owns h-cols
// [(wid&3)*32,+32) for ALL 4 gates -> elementwise lane-local AND every
// c-read / h,c-write covers a full 128B line per row.
// LDS: xh[2][64 rows][32 slots of 16B] bf16, slot swizzle s^(row&7).
__global__ __launch_bounds__(512, 4)
void lstm_fused(const float* __restrict__ x, const float* __restrict__ hin,
                const float* __restrict__ cin, const bf16x8* __restrict__ Wf,
                const float* __restrict__ bcat, float* __restrict__ out, int Btot){
  __shared__ __attribute__((aligned(16))) bf16x8 xh[2][TR * 32];

  const int tid  = threadIdx.x;
  const int l    = tid & 63;
  const int wid  = tid >> 6;       // 0..7
  const int mgrp = wid >> 2;       // 0/1  (row half)
  const int hs   = wid & 3;        // 32-col slice
  const int l15  = l & 15;
  const int lg   = l >> 4;         // 0..3

  float bb[4][2];
  #pragma unroll
  for (int g = 0; g < 4; ++g)
    #pragma unroll
    for (int t = 0; t < 2; ++t)
      bb[g][t] = bcat[g * 128 + hs * 32 + t * 16 + l15];

  const bf16x8* wv = Wf + (size_t)hs * 4096 + l;  // [(g*2+t)*8+ks] stride 64

  // staging map: thread covers (row = i*32 + tid>>4, slot8 = tid&15), i=0,1
  const int srow = tid >> 4;       // 0..31
  const int sc8  = tid & 15;       // 16B-slot within x (or h) half

  const size_t o1 = (size_t)Btot * DH;
  size_t tile = (size_t)blockIdx.x * NT;

  // ---- prologue: stage tile 0 into buf 0
  {
    const float* xb = x   + tile * TR * DH;
    const float* hb = hin + tile * TR * DH;
    #pragma unroll
    for (int i = 0; i < 2; ++i){
      int row = i * 32 + srow;
      const float* px = xb + row * DH + sc8 * 8;
      const float* ph = hb + row * DH + sc8 * 8;
      float4 a0 = *(const float4*)px, a1 = *(const float4*)(px + 4);
      float4 b0 = *(const float4*)ph, b1 = *(const float4*)(ph + 4);
      i32x4 p;
      p[0] = pk2(a0.x, a0.y); p[1] = pk2(a0.z, a0.w);
      p[2] = pk2(a1.x, a1.y); p[3] = pk2(a1.z, a1.w);
      xh[0][row * 32 + ( sc8       ^ (row & 7))] = __builtin_bit_cast(bf16x8, p);
      p[0] = pk2(b0.x, b0.y); p[1] = pk2(b0.z, b0.w);
      p[2] = pk2(b1.x, b1.y); p[3] = pk2(b1.z, b1.w);
      xh[0][row * 32 + ((16 + sc8) ^ (row & 7))] = __builtin_bit_cast(bf16x8, p);
    }
  }
  __syncthreads();

  for (int it = 0; it < NT; ++it, ++tile){
    const int cb = it & 1, nb = cb ^ 1;
    const size_t rowb = tile * TR;
    const bool pf = (it + 1 < NT);
    const float* nxb = x   + (rowb + TR) * DH;
    const float* nhb = hin + (rowb + TR) * DH;

    // issue next-tile x loads (land while ks 0..3 compute)
    float4 sx[4];
    if (pf){
      #pragma unroll
      for (int i = 0; i < 2; ++i){
        const float* px = nxb + (i * 32 + srow) * DH + sc8 * 8;
        sx[i * 2]     = *(const float4*)px;
        sx[i * 2 + 1] = *(const float4*)(px + 4);
      }
    }

    f32x4 acc[2][4][2];
    #pragma unroll
    for (int m = 0; m < 2; ++m)
      #pragma unroll
      for (int g = 0; g < 4; ++g)
        #pragma unroll
        for (int t = 0; t < 2; ++t)
          acc[m][g][t] = (f32x4){0.f, 0.f, 0.f, 0.f};

    // ---- ks 0..3 : x half (slots 0..15)
    #pragma unroll
    for (int ks = 0; ks < 4; ++ks){
      bf16x8 a[2];
      #pragma unroll
      for (int m = 0; m < 2; ++m){
        int row = mgrp * 32 + m * 16 + l15;
        a[m] = xh[cb][row * 32 + ((ks * 4 + lg) ^ (row & 7))];
      }
      #pragma unroll
      for (int g = 0; g < 4; ++g){
        #pragma unroll
        for (int t = 0; t < 2; ++t){
          bf16x8 bw = wv[(((g * 2 + t) * 8) + ks) * 64];
          acc[0][g][t] = __builtin_amdgcn_mfma_f32_16x16x32_bf16(a[0], bw, acc[0][g][t], 0, 0, 0);
          acc[1][g][t] = __builtin_amdgcn_mfma_f32_16x16x32_bf16(a[1], bw, acc[1][g][t], 0, 0, 0);
        }
      }
    }

    // write next-tile x to other buf; issue next-tile h loads
    float4 sh[4];
    if (pf){
      #pragma unroll
      for (int i = 0; i < 2; ++i){
        int row = i * 32 + srow;
        i32x4 p;
        p[0] = pk2(sx[i*2].x, sx[i*2].y); p[1] = pk2(sx[i*2].z, sx[i*2].w);
        p[2] = pk2(sx[i*2+1].x, sx[i*2+1].y); p[3] = pk2(sx[i*2+1].z, sx[i*2+1].w);
        xh[nb][row * 32 + (sc8 ^ (row & 7))] = __builtin_bit_cast(bf16x8, p);
        const float* ph = nhb + row * DH + sc8 * 8;
        sh[i * 2]     = *(const float4*)ph;
        sh[i * 2 + 1] = *(const float4*)(ph + 4);
      }
    }

    // ---- ks 4..7 : h half (slots 16..31)
    #pragma unroll
    for (int ks = 4; ks < 8; ++ks){
      bf16x8 a[2];
      #pragma unroll
      for (int m = 0; m < 2; ++m){
        int row = mgrp * 32 + m * 16 + l15;
        a[m] = xh[cb][row * 32 + ((ks * 4 + lg) ^ (row & 7))];
      }
      #pragma unroll
      for (int g = 0; g < 4; ++g){
        #pragma unroll
        for (int t = 0; t < 2; ++t){
          bf16x8 bw = wv[(((g * 2 + t) * 8) + ks) * 64];
          acc[0][g][t] = __builtin_amdgcn_mfma_f32_16x16x32_bf16(a[0], bw, acc[0][g][t], 0, 0, 0);
          acc[1][g][t] = __builtin_amdgcn_mfma_f32_16x16x32_bf16(a[1], bw, acc[1][g][t], 0, 0, 0);
        }
      }
    }

    // write next-tile h
    if (pf){
      #pragma unroll
      for (int i = 0; i < 2; ++i){
        int row = i * 32 + srow;
        i32x4 p;
        p[0] = pk2(sh[i*2].x, sh[i*2].y); p[1] = pk2(sh[i*2].z, sh[i*2].w);
        p[2] = pk2(sh[i*2+1].x, sh[i*2+1].y); p[3] = pk2(sh[i*2+1].z, sh[i*2+1].w);
        xh[nb][row * 32 + ((16 + sc8) ^ (row & 7))] = __builtin_bit_cast(bf16x8, p);
      }
    }
    __syncthreads();   // next buf ready; epilogue overlaps other waves' k-loop

    // ---- epilogue tile it: full 128B line per (row): cols [hs*32, hs*32+32)
    #pragma unroll
    for (int m = 0; m < 2; ++m){
      #pragma unroll
      for (int r = 0; r < 4; ++r){
        const size_t row = rowb + mgrp * 32 + m * 16 + lg * 4 + r;  // C/D row
        #pragma unroll
        for (int t = 0; t < 2; ++t){
          const size_t idx = row * DH + hs * 32 + t * 16 + l15;     // C/D col
          float gi = acc[m][0][t][r] + bb[0][t];
          float gf = acc[m][1][t][r] + bb[1][t];
          float gc = acc[m][2][t][r] + bb[2][t];
          float go = acc[m][3][t][r] + bb[3][t];
          float i_t = fsigmoid(gi);
          float f_t = fsigmoid(gf);
          float g_t = ftanhf(gc);
          float o_t = fsigmoid(go);
          float cn = f_t * cin[idx] + i_t * g_t;
          float hn = o_t * ftanhf(cn);
          out[idx]          = hn;
          out[o1 + idx]     = hn;
          out[2 * o1 + idx] = cn;
        }
      }
    }
  }
}

extern "C" void kernel_launch(void* const* d_in, const int* in_sizes, int n_in,
                              void* d_out, int out_size, void* d_ws, size_t ws_size,
                              hipStream_t stream){
  const float* x  = (const float*)d_in[0];
  const float* ht = (const float*)d_in[1];
  const float* ct = (const float*)d_in[2];
  u16x8* Wf   = (u16x8*)d_ws;                        // 16384 * 16B = 256KB
  float* bcat = (float*)((char*)d_ws + 16384 * 16);  // +2KB
  const int Btot = in_sizes[0] / DH;

  prep_weights<<<64, 256, 0, stream>>>(
      (const float*)d_in[3],  (const float*)d_in[4],  (const float*)d_in[5],
      (const float*)d_in[6],  (const float*)d_in[7],  (const float*)d_in[8],
      (const float*)d_in[9],  (const float*)d_in[10], (const float*)d_in[11],
      (const float*)d_in[12], (const float*)d_in[13], (const float*)d_in[14],
      Wf, bcat);

  const int nblocks = Btot / (TR * NT);   // 512 for B=262144
  lstm_fused<<<nblocks, 512, 0, stream>>>(x, ht, ct, (const bf16x8*)Wf, bcat,
                                          (float*)d_out, Btot);
}

// Round 6
// 325.068 us; speedup vs baseline: 2.8444x; 2.8444x over previous
//
#include <hip/hip_runtime.h>

#define DH 128   // D_IN == D_H == 128
#define TR 32    // rows per tile (per block)

typedef __attribute__((ext_vector_type(8))) short bf16x8;
typedef __attribute__((ext_vector_type(8))) unsigned short u16x8;
typedef __attribute__((ext_vector_type(4))) float f32x4;
typedef __attribute__((ext_vector_type(4))) int   i32x4;

__device__ inline unsigned rnd_bf16(float f){
  unsigned u = __builtin_bit_cast(unsigned, f);
  u += 0x7fffu + ((u >> 16) & 1u);   // RNE
  return u;
}
__device__ inline int pk2(float a, float b){
  unsigned ua = rnd_bf16(a), ub = rnd_bf16(b);
  return (int)((ua >> 16) | (ub & 0xffff0000u));
}
__device__ inline float fsigmoid(float v){
  float e = __builtin_amdgcn_exp2f(v * -1.442695040888963f);
  return __builtin_amdgcn_rcpf(1.0f + e);
}
__device__ inline float ftanhf(float v){
  float e = __builtin_amdgcn_exp2f(v * 2.885390081777927f); // e^{2v}
  return 1.0f - 2.0f * __builtin_amdgcn_rcpf(1.0f + e);
}

// Wf[hs 4][g 4][t 2][ks 8][lane 64] 16B fragments: lane (l15,lg) holds
// ncol = g*128 + hs*32 + t*16 + l15, k = ks*32 + lg*8 .. +8 (k<128: W_x, else W_h).
__global__ void prep_weights(const float* __restrict__ Wxi, const float* __restrict__ Whi, const float* __restrict__ bi,
                             const float* __restrict__ Wxf, const float* __restrict__ Whf, const float* __restrict__ bf_,
                             const float* __restrict__ Wxc, const float* __restrict__ Whc, const float* __restrict__ bc,
                             const float* __restrict__ Wxo, const float* __restrict__ Who, const float* __restrict__ bo,
                             u16x8* __restrict__ Wf, float* __restrict__ bcat){
  int gid  = blockIdx.x * 256 + threadIdx.x;   // 0..16383
  int lane = gid & 63;
  int ks   = (gid >> 6) & 7;
  int t    = (gid >> 9) & 1;
  int g    = (gid >> 10) & 3;
  int hsv  = (gid >> 12) & 3;
  int l15 = lane & 15, lg = lane >> 4;
  int hcol = hsv * 32 + t * 16 + l15;
  int kb   = ks * 32 + lg * 8;
  const float* Wx = (g == 0) ? Wxi : (g == 1) ? Wxf : (g == 2) ? Wxc : Wxo;
  const float* Wh = (g == 0) ? Whi : (g == 1) ? Whf : (g == 2) ? Whc : Who;
  u16x8 o;
  #pragma unroll
  for (int j = 0; j < 8; ++j){
    int k = kb + j;
    float v = (k < 128) ? Wx[k * DH + hcol] : Wh[(k - 128) * DH + hcol];
    o[j] = (unsigned short)(rnd_bf16(v) >> 16);
  }
  Wf[gid] = o;
  if (gid < 512){
    int gg = gid >> 7, hc = gid & 127;
    const float* bp = (gg == 0) ? bi : (gg == 1) ? bf_ : (gg == 2) ? bc : bo;
    bcat[gid] = bp[hc];
  }
}

// One 32-row tile per block. 256 thr = 4 waves; wave w owns h-cols
// [w*32, w*32+32) for ALL 4 gates (lane-local elementwise, full 128B
// line per row on c-read/h,c-write). Reg-staged bf16 LDS (16KB), one barrier.
__global__ __launch_bounds__(256, 4)
void lstm_fused(const float* __restrict__ x, const float* __restrict__ hin,
                const float* __restrict__ cin, const bf16x8* __restrict__ Wf,
                const float* __restrict__ bcat, float* __restrict__ out, int Btot){
  __shared__ __attribute__((aligned(16))) bf16x8 xh[TR * 32];  // 16 KB

  const int tid = threadIdx.x;
  const int l   = tid & 63;
  const int hs  = tid >> 6;        // wave id = col-slice 0..3
  const int l15 = l & 15;
  const int lg  = l >> 4;          // 0..3
  const size_t rowb = (size_t)blockIdx.x * TR;

  // ---- staging loads: thread covers (row = tid>>3, 16 cols at (tid&7)*16)
  const int srow = tid >> 3;       // 0..31
  const int scol = (tid & 7) * 16; // float col base
  const float* px = x   + (rowb + srow) * DH + scol;
  const float* ph = hin + (rowb + srow) * DH + scol;
  float4 x0 = *(const float4*)(px);      float4 x1 = *(const float4*)(px + 4);
  float4 x2 = *(const float4*)(px + 8);  float4 x3 = *(const float4*)(px + 12);
  float4 h0 = *(const float4*)(ph);      float4 h1 = *(const float4*)(ph + 4);
  float4 h2 = *(const float4*)(ph + 8);  float4 h3 = *(const float4*)(ph + 12);

  // ---- c prefetch (nontemporal: read-once, keep out of L2)
  float cr[2][2][4];
  #pragma unroll
  for (int m = 0; m < 2; ++m)
    #pragma unroll
    for (int t = 0; t < 2; ++t)
      #pragma unroll
      for (int r = 0; r < 4; ++r)
        cr[m][t][r] = __builtin_nontemporal_load(
            cin + (rowb + m * 16 + lg * 4 + r) * DH + hs * 32 + t * 16 + l15);

  // ---- pack + LDS write (slot swizzle s^(row&7); 2-way max conflict = free)
  {
    const int sw = srow & 7;
    const int s0 = (tid & 7) * 2;        // x-half slots
    i32x4 p;
    p[0] = pk2(x0.x, x0.y); p[1] = pk2(x0.z, x0.w);
    p[2] = pk2(x1.x, x1.y); p[3] = pk2(x1.z, x1.w);
    xh[srow * 32 + ( s0          ^ sw)] = __builtin_bit_cast(bf16x8, p);
    p[0] = pk2(x2.x, x2.y); p[1] = pk2(x2.z, x2.w);
    p[2] = pk2(x3.x, x3.y); p[3] = pk2(x3.z, x3.w);
    xh[srow * 32 + ((s0 + 1)     ^ sw)] = __builtin_bit_cast(bf16x8, p);
    p[0] = pk2(h0.x, h0.y); p[1] = pk2(h0.z, h0.w);
    p[2] = pk2(h1.x, h1.y); p[3] = pk2(h1.z, h1.w);
    xh[srow * 32 + ((16 + s0)    ^ sw)] = __builtin_bit_cast(bf16x8, p);
    p[0] = pk2(h2.x, h2.y); p[1] = pk2(h2.z, h2.w);
    p[2] = pk2(h3.x, h3.y); p[3] = pk2(h3.z, h3.w);
    xh[srow * 32 + ((16 + s0 + 1)^ sw)] = __builtin_bit_cast(bf16x8, p);
  }
  __syncthreads();

  float bb[4][2];
  #pragma unroll
  for (int g = 0; g < 4; ++g)
    #pragma unroll
    for (int t = 0; t < 2; ++t)
      bb[g][t] = bcat[g * 128 + hs * 32 + t * 16 + l15];

  const bf16x8* wv = Wf + (size_t)hs * 4096 + l;  // [(g*2+t)*8+ks] stride 64

  f32x4 acc[2][4][2];
  #pragma unroll
  for (int m = 0; m < 2; ++m)
    #pragma unroll
    for (int g = 0; g < 4; ++g)
      #pragma unroll
      for (int t = 0; t < 2; ++t)
        acc[m][g][t] = (f32x4){0.f, 0.f, 0.f, 0.f};

  #pragma unroll
  for (int ks = 0; ks < 8; ++ks){
    bf16x8 a[2];
    #pragma unroll
    for (int m = 0; m < 2; ++m){
      const int row = m * 16 + l15;
      a[m] = xh[row * 32 + ((ks * 4 + lg) ^ (row & 7))];
    }
    #pragma unroll
    for (int g = 0; g < 4; ++g){
      #pragma unroll
      for (int t = 0; t < 2; ++t){
        bf16x8 bw = wv[(((g * 2 + t) * 8) + ks) * 64];
        acc[0][g][t] = __builtin_amdgcn_mfma_f32_16x16x32_bf16(a[0], bw, acc[0][g][t], 0, 0, 0);
        acc[1][g][t] = __builtin_amdgcn_mfma_f32_16x16x32_bf16(a[1], bw, acc[1][g][t], 0, 0, 0);
      }
    }
  }

  // ---- epilogue: full 128B line per row (cols [hs*32, hs*32+32)); nt stores
  const size_t o1 = (size_t)Btot * DH;
  #pragma unroll
  for (int m = 0; m < 2; ++m){
    #pragma unroll
    for (int r = 0; r < 4; ++r){
      const size_t row = rowb + m * 16 + lg * 4 + r;
      #pragma unroll
      for (int t = 0; t < 2; ++t){
        const size_t idx = row * DH + hs * 32 + t * 16 + l15;
        float gi = acc[m][0][t][r] + bb[0][t];
        float gf = acc[m][1][t][r] + bb[1][t];
        float gc = acc[m][2][t][r] + bb[2][t];
        float go = acc[m][3][t][r] + bb[3][t];
        float i_t = fsigmoid(gi);
        float f_t = fsigmoid(gf);
        float g_t = ftanhf(gc);
        float o_t = fsigmoid(go);
        float cn = f_t * cr[m][t][r] + i_t * g_t;
        float hn = o_t * ftanhf(cn);
        __builtin_nontemporal_store(hn, out + idx);
        __builtin_nontemporal_store(hn, out + o1 + idx);
        __builtin_nontemporal_store(cn, out + 2 * o1 + idx);
      }
    }
  }
}

extern "C" void kernel_launch(void* const* d_in, const int* in_sizes, int n_in,
                              void* d_out, int out_size, void* d_ws, size_t ws_size,
                              hipStream_t stream){
  const float* x  = (const float*)d_in[0];
  const float* ht = (const float*)d_in[1];
  const float* ct = (const float*)d_in[2];
  u16x8* Wf   = (u16x8*)d_ws;                        // 16384 * 16B = 256KB
  float* bcat = (float*)((char*)d_ws + 16384 * 16);  // +2KB
  const int Btot = in_sizes[0] / DH;

  prep_weights<<<64, 256, 0, stream>>>(
      (const float*)d_in[3],  (const float*)d_in[4],  (const float*)d_in[5],
      (const float*)d_in[6],  (const float*)d_in[7],  (const float*)d_in[8],
      (const float*)d_in[9],  (const float*)d_in[10], (const float*)d_in[11],
      (const float*)d_in[12], (const float*)d_in[13], (const float*)d_in[14],
      Wf, bcat);

  lstm_fused<<<Btot / TR, 256, 0, stream>>>(x, ht, ct, (const bf16x8*)Wf, bcat,
                                            (float*)d_out, Btot);
}